// Round 11
// baseline (596.041 us; speedup 1.0000x reference)
//
#include <hip/hip_runtime.h>
#include <hip/hip_bf16.h>

typedef long long TLONG;
typedef float  f32x4_t  __attribute__((ext_vector_type(4)));
typedef short  s16x8_t  __attribute__((ext_vector_type(8)));
typedef short  s16x4_t  __attribute__((ext_vector_type(4)));
typedef __bf16 bf16x8_t __attribute__((ext_vector_type(8)));

#define MDIM 32768
#define NDIM 1024
#define KDIM 1024
#define EPSV 1e-6f

#define BARRIER() asm volatile("s_barrier" ::: "memory")
#define SBAR() __builtin_amdgcn_sched_barrier(0)

__device__ __forceinline__ unsigned short f2bf_bits(float f) {
  __hip_bfloat16 h = __float2bfloat16(f);
  return __builtin_bit_cast(unsigned short, h);
}
__device__ __forceinline__ float bf2f(unsigned short u) {
  unsigned int x = ((unsigned int)u) << 16;
  return __builtin_bit_cast(float, x);
}
// async global->LDS, 16B per lane. LDS dest must be wave-uniform base + lane*16.
__device__ __forceinline__ void load_lds16(const void* g, void* l) {
  __builtin_amdgcn_global_load_lds((const __attribute__((address_space(1))) void*)g,
                                   (__attribute__((address_space(3))) void*)l, 16, 0, 0);
}

// nt LOADS (f32 read exactly once -> keep out of L3); REGULAR stores (outputs
// are re-read by the GEMMs -> want L3 residency). [R8: nt stores cost +26MB refetch]
__device__ __forceinline__ void conv8(const float* __restrict__ in,
                                      unsigned short* __restrict__ out, TLONG i) {
  f32x4_t a = __builtin_nontemporal_load(reinterpret_cast<const f32x4_t*>(in + i));
  f32x4_t b = __builtin_nontemporal_load(reinterpret_cast<const f32x4_t*>(in + i + 4));
  s16x8_t o;
  o[0] = (short)f2bf_bits(a[0]); o[1] = (short)f2bf_bits(a[1]);
  o[2] = (short)f2bf_bits(a[2]); o[3] = (short)f2bf_bits(a[3]);
  o[4] = (short)f2bf_bits(b[0]); o[5] = (short)f2bf_bits(b[1]);
  o[6] = (short)f2bf_bits(b[2]); o[7] = (short)f2bf_bits(b[3]);
  *reinterpret_cast<s16x8_t*>(out + i) = o;
}

// ---------------------------------------------------------------- converts
__global__ __launch_bounds__(256) void convert3_f32_bf16(
    const float* __restrict__ a, const float* __restrict__ b, const float* __restrict__ c,
    unsigned short* __restrict__ oa, unsigned short* __restrict__ ob,
    unsigned short* __restrict__ oc) {
  int blk = blockIdx.x;
  const float* in; unsigned short* out;
  if (blk < 2048)      { in = a; out = oa; }
  else if (blk < 4096) { in = b; out = ob; blk -= 2048; }
  else                 { in = c; out = oc; blk -= 4096; }
  const TLONG n = 33554432LL;
  TLONG i = ((TLONG)blk * 256 + threadIdx.x) * 8;
  const TLONG stride = 2048LL * 256 * 8;
  for (; i < n; i += stride) conv8(in, out, i);
}
__global__ __launch_bounds__(256) void convertW_f32_bf16(
    const float* __restrict__ a, const float* __restrict__ b, const float* __restrict__ c,
    const float* __restrict__ d, unsigned short* __restrict__ oa,
    unsigned short* __restrict__ ob, unsigned short* __restrict__ oc,
    unsigned short* __restrict__ od) {
  int blk = blockIdx.x;
  const float* in; unsigned short* out;
  if (blk < 512)       { in = a; out = oa; }
  else if (blk < 1024) { in = b; out = ob; blk -= 512; }
  else if (blk < 1536) { in = c; out = oc; blk -= 1024; }
  else                 { in = d; out = od; blk -= 1536; }
  TLONG i = ((TLONG)blk * 256 + threadIdx.x) * 8;
  conv8(in, out, i);
}

// ---------------------------------------------------------------- GEMM 256x256, phase-pipelined reads
// C[m][n] = f(sum_k A[m][k]*W[n][k] + bias[n]); M=32768, N=K=1024.
// BM=BN=256, BK=64; 512 thr = 8 waves (2M x 4N); wave tile 128x64.
// LDS 128 KiB = 2 buf x (A 32KB | B 32KB). Read groups G1=Af0-3+Bf0-1(12),
// G2=Af4-7(8), G3=Bf2-3(4). Each group is issued ONE PHASE BEFORE its MFMA
// (LDS latency hides under the previous quad + barrier), waits stay counted:
//  P1: issue G2; stage Bh0(kt+1); bar; lgkm(8)  [G1 done]; quad(0,0); bar
//  P2: issue G3; stage Bh1(kt+1); bar; lgkm(4)  [G2 done]; quad(4,0); bar
//  P3: stage Ah0(kt+2)->buf p;    bar; lgkm(0)  [G3 done]; quad(0,2); bar
//  P4: stage Ah1(kt+2);           bar; quad(4,2); vmcnt(4) [B(kt+1) landed,
//      A(kt+2) in flight - never 0]; issue G1(kt+1) from buf q; bar
// Hazards: Ah0/Ah1 overwrite follows the lgkm+barrier retiring Af0-3/Af4-7;
// G1(kt+1)'s B reads issue only after the vmcnt that lands B(kt+1); vmem is
// in-order so vmcnt(4) leaves exactly A(kt+2)x4 outstanding.
template <int FMAP, int OUT>
__global__ __launch_bounds__(512, 2) void gemm256(
    const unsigned short* __restrict__ A, const unsigned short* __restrict__ W,
    const float* __restrict__ bias, void* __restrict__ Cout) {
  __shared__ short lds[65536];                    // [2 buf][A 16384 | B 16384] shorts
  const int bid = blockIdx.x;                     // 512 blocks
  const int swz = (bid & 7) * 64 + (bid >> 3);    // XCD-chunked (512%8==0)
  const int mt = swz >> 2;                        // 0..127
  const int nt = swz & 3;                         // 0..3

  const int tid = threadIdx.x;
  const int lane = tid & 63;
  const int w = tid >> 6;
  const int wr = w >> 2, wc = w & 3;
  const int l15 = lane & 15, lh = lane >> 4;

  const int arow0 = mt * 256, brow0 = nt * 256;

  auto stage_half = [&](const unsigned short* __restrict__ src, int ldsOff,
                        int grow, int k0) {
#pragma unroll
    for (int i = 0; i < 2; ++i) {
      const int c = i * 512 + tid;                // 0..1023
      const int r = c >> 3, ps = c & 7;
      load_lds16(src + (grow + r) * KDIM + k0 + ((ps ^ (r & 7)) * 8),
                 &lds[ldsOff + c * 8]);
    }
  };

  f32x4_t acc[8][4];
#pragma unroll
  for (int m = 0; m < 8; ++m)
#pragma unroll
    for (int n = 0; n < 4; ++n) acc[m][n] = (f32x4_t)0.0f;

  s16x8_t Af[8][2], Bf[4][2];

  auto rdA = [&](int pb, int m, int ks) -> s16x8_t {
    const int row = wr * 128 + m * 16 + l15;
    return *reinterpret_cast<const s16x8_t*>(
        &lds[pb + row * 64 + (((ks * 4 + lh) ^ (row & 7)) * 8)]);
  };
  auto rdB = [&](int pb, int n, int ks) -> s16x8_t {
    const int row = wc * 64 + n * 16 + l15;
    return *reinterpret_cast<const s16x8_t*>(
        &lds[pb + 16384 + row * 64 + (((ks * 4 + lh) ^ (row & 7)) * 8)]);
  };
  auto quad = [&](int mb, int nl) {
    __builtin_amdgcn_s_setprio(1);
#pragma unroll
    for (int m = 0; m < 4; ++m)
#pragma unroll
      for (int n = 0; n < 2; ++n)
#pragma unroll
        for (int ks = 0; ks < 2; ++ks)
          acc[mb + m][nl + n] = __builtin_amdgcn_mfma_f32_16x16x32_bf16(
              __builtin_bit_cast(bf16x8_t, Af[mb + m][ks]),
              __builtin_bit_cast(bf16x8_t, Bf[nl + n][ks]),
              acc[mb + m][nl + n], 0, 0, 0);
    __builtin_amdgcn_s_setprio(0);
  };
  auto issueG1 = [&](int b) {                     // Af0-3 + Bf0-1: 12 reads
#pragma unroll
    for (int m = 0; m < 4; ++m)
#pragma unroll
      for (int ks = 0; ks < 2; ++ks) Af[m][ks] = rdA(b, m, ks);
#pragma unroll
    for (int n = 0; n < 2; ++n)
#pragma unroll
      for (int ks = 0; ks < 2; ++ks) Bf[n][ks] = rdB(b, n, ks);
  };

  // prologue: A(0),B(0) -> buf0; A(1) -> buf1 (12 gloads/thread); G1(0) issued.
  stage_half(A, 0,             arow0,       0);
  stage_half(A, 8192,          arow0 + 128, 0);
  stage_half(W, 16384,         brow0,       0);
  stage_half(W, 16384 + 8192,  brow0 + 128, 0);
  stage_half(A, 32768,         arow0,       64);
  stage_half(A, 32768 + 8192,  arow0 + 128, 64);
  asm volatile("s_waitcnt vmcnt(4)" ::: "memory");   // A(0),B(0) landed; A(1) flying
  SBAR();
  BARRIER();
  issueG1(0);
  SBAR();

  for (int kt = 0; kt < 16; ++kt) {
    const int p = kt & 1;
    const int pb = p * 32768, qb = 32768 - pb;
    const int k1 = ((kt + 1) & 15) * 64;
    const int k2 = ((kt + 2) & 15) * 64;   // wrapped tail: junk reload, never read
    // ---- P1: issue G2; stage Bh0(kt+1); lgkm(8) -> G1 done; quad(0,0)
#pragma unroll
    for (int m = 0; m < 4; ++m)
#pragma unroll
      for (int ks = 0; ks < 2; ++ks) Af[4 + m][ks] = rdA(pb, 4 + m, ks);
    SBAR();
    stage_half(W, qb + 16384, brow0, k1);
    BARRIER();
    asm volatile("s_waitcnt lgkmcnt(8)" ::: "memory");
    SBAR();
    quad(0, 0);
    BARRIER();
    // ---- P2: issue G3; stage Bh1(kt+1); lgkm(4) -> G2 done; quad(4,0)
#pragma unroll
    for (int n = 2; n < 4; ++n)
#pragma unroll
      for (int ks = 0; ks < 2; ++ks) Bf[n][ks] = rdB(pb, n, ks);
    SBAR();
    stage_half(W, qb + 16384 + 8192, brow0 + 128, k1);
    BARRIER();
    asm volatile("s_waitcnt lgkmcnt(4)" ::: "memory");
    SBAR();
    quad(4, 0);
    BARRIER();
    // ---- P3: stage Ah0(kt+2) into buf p (Af0-3 readers retired at P1);
    //          lgkm(0) -> G3 done; quad(0,2)
    stage_half(A, pb, arow0, k2);
    BARRIER();
    asm volatile("s_waitcnt lgkmcnt(0)" ::: "memory");
    SBAR();
    quad(0, 2);
    BARRIER();
    // ---- P4: stage Ah1(kt+2) (Af4-7 retired at P2); quad(4,2);
    //          vmcnt(4) -> B(kt+1)+A(kt+1) landed, A(kt+2) in flight;
    //          issue G1(kt+1) from buf q
    stage_half(A, pb + 8192, arow0 + 128, k2);
    BARRIER();
    quad(4, 2);
    asm volatile("s_waitcnt vmcnt(4)" ::: "memory");
    SBAR();
    issueG1(qb);
    SBAR();
    BARRIER();
  }

  // epilogue: C/D layout col = lane&15, row = (lane>>4)*4 + j  [m89/m91]
#pragma unroll
  for (int n = 0; n < 4; ++n) {
    const int col = nt * 256 + wc * 64 + n * 16 + l15;
    const float bv = bias[col];
#pragma unroll
    for (int m = 0; m < 8; ++m) {
      const int row0 = mt * 256 + wr * 128 + m * 16 + lh * 4;
      if (OUT == 2) {
        const int b = row0 >> 13, tl = row0 & 8191;
        const int h = col >> 6, d = col & 63;
        s16x4_t o;
#pragma unroll
        for (int j = 0; j < 4; ++j) {
          float v = acc[m][n][j] + bv;
          if (FMAP) v = (v > 0.0f) ? (v + 1.0f) : __expf(v);
          o[j] = (short)f2bf_bits(v);
        }
        *reinterpret_cast<s16x4_t*>(
            reinterpret_cast<unsigned short*>(Cout) +
            (((b * 16 + h) * 64 + d) * 8192 + tl)) = o;
      } else {
#pragma unroll
        for (int j = 0; j < 4; ++j) {
          float v = acc[m][n][j] + bv;
          if (FMAP) v = (v > 0.0f) ? (v + 1.0f) : __expf(v);  // elu(x)+1
          if (OUT == 1)
            __builtin_nontemporal_store(v,                    // final f32: never re-read
                &reinterpret_cast<float*>(Cout)[(row0 + j) * NDIM + col]);
          else
            reinterpret_cast<unsigned short*>(Cout)[(row0 + j) * NDIM + col] = f2bf_bits(v);
        }
      }
    }
  }
}

// ---------------------------------------------------------------- kv + k_sum (MFMA, streaming)
// Inputs transposed: kT[bh][d][8192 t], vT[bh][e][8192 t] (bf16).
__global__ __launch_bounds__(256) void kv_ksum_mfma(
    const unsigned short* __restrict__ kT, const unsigned short* __restrict__ vT,
    float* __restrict__ kvT, float* __restrict__ ksum) {
  const int bid = blockIdx.x;
  const int bh = bid >> 4, ch = bid & 15;
  const int tid = threadIdx.x;
  const int lane = tid & 63, w = tid >> 6;
  const int l15 = lane & 15, lh = lane >> 4;
  const int dblk = (w >> 1) * 32, eblk = (w & 1) * 32;

  f32x4_t acc[2][2];
#pragma unroll
  for (int m = 0; m < 2; ++m)
#pragma unroll
    for (int n = 0; n < 2; ++n) acc[m][n] = (f32x4_t)0.0f;
  float ks0 = 0.f, ks1 = 0.f;

  const int tbase = ch * 512 + lh * 8;
  const unsigned short* ka = kT + (bh * 64 + dblk + l15) * 8192 + tbase;
  const unsigned short* va = vT + (bh * 64 + eblk + l15) * 8192 + tbase;

  for (int t0 = 0; t0 < 512; t0 += 32) {
    s16x8_t ar[2], br[2];
#pragma unroll
    for (int m = 0; m < 2; ++m)
      ar[m] = *reinterpret_cast<const s16x8_t*>(ka + m * 16 * 8192 + t0);
#pragma unroll
    for (int n = 0; n < 2; ++n)
      br[n] = *reinterpret_cast<const s16x8_t*>(va + n * 16 * 8192 + t0);
#pragma unroll
    for (int m = 0; m < 2; ++m)
#pragma unroll
      for (int n = 0; n < 2; ++n)
        acc[m][n] = __builtin_amdgcn_mfma_f32_16x16x32_bf16(
            __builtin_bit_cast(bf16x8_t, ar[m]),
            __builtin_bit_cast(bf16x8_t, br[n]), acc[m][n], 0, 0, 0);
    if (eblk == 0) {
#pragma unroll
      for (int i = 0; i < 8; ++i) ks0 += bf2f((unsigned short)ar[0][i]);
#pragma unroll
      for (int i = 0; i < 8; ++i) ks1 += bf2f((unsigned short)ar[1][i]);
    }
  }

  if (eblk == 0) {
    ks0 += __shfl_xor(ks0, 16); ks0 += __shfl_xor(ks0, 32);
    ks1 += __shfl_xor(ks1, 16); ks1 += __shfl_xor(ks1, 32);
    if (lh == 0) {
      atomicAdd(&ksum[bh * 64 + dblk + l15], ks0);
      atomicAdd(&ksum[bh * 64 + dblk + 16 + l15], ks1);
    }
  }
#pragma unroll
  for (int n = 0; n < 2; ++n) {
    const int e = eblk + n * 16 + l15;
#pragma unroll
    for (int m = 0; m < 2; ++m) {
      const int d0 = dblk + m * 16 + lh * 4;
#pragma unroll
      for (int j = 0; j < 4; ++j)
        atomicAdd(&kvT[(bh * 64 + e) * 64 + d0 + j], acc[m][n][j]);
    }
  }
}

// ---------------------------------------------------------------- out = q@kv / (q.ksum+eps)
__global__ __launch_bounds__(256) void attn_apply_kernel(
    const unsigned short* __restrict__ qf, const float* __restrict__ kvT,
    const float* __restrict__ ksum, unsigned short* __restrict__ att) {
  const int bid = blockIdx.x;                     // 2048
  const int swz = (bid & 7) * 256 + (bid >> 3);
  const int bh = swz >> 5;
  const int tile = swz & 31;
  const int b = bh >> 4, h = bh & 15;
  const int tid = threadIdx.x;
  const int lane = tid & 63, w = tid >> 6;
  const int l15 = lane & 15, lh = lane >> 4;

  float ksr[16];
#pragma unroll
  for (int i = 0; i < 16; ++i) ksr[i] = ksum[bh * 64 + lh * 16 + i];

  bf16x8_t bfrag[2][4];
#pragma unroll
  for (int ks2 = 0; ks2 < 2; ++ks2)
#pragma unroll
    for (int n = 0; n < 4; ++n) {
      const float* p = kvT + (bh * 64 + n * 16 + l15) * 64 + ks2 * 32 + lh * 8;
      f32x4_t p0 = *reinterpret_cast<const f32x4_t*>(p);
      f32x4_t p1 = *reinterpret_cast<const f32x4_t*>(p + 4);
      s16x8_t t;
      t[0] = (short)f2bf_bits(p0[0]); t[1] = (short)f2bf_bits(p0[1]);
      t[2] = (short)f2bf_bits(p0[2]); t[3] = (short)f2bf_bits(p0[3]);
      t[4] = (short)f2bf_bits(p1[0]); t[5] = (short)f2bf_bits(p1[1]);
      t[6] = (short)f2bf_bits(p1[2]); t[7] = (short)f2bf_bits(p1[3]);
      bfrag[ks2][n] = __builtin_bit_cast(bf16x8_t, t);
    }

  const int rbase = b * 8192 + tile * 256 + w * 64;
  f32x4_t acc[4][4];
#pragma unroll
  for (int m = 0; m < 4; ++m)
#pragma unroll
    for (int n = 0; n < 4; ++n) acc[m][n] = (f32x4_t)0.0f;
  float rden[4][4];

#pragma unroll
  for (int m = 0; m < 4; ++m) {
    const int row = rbase + m * 16 + l15;
    const unsigned short* qrow = qf + row * 1024 + h * 64;
    bf16x8_t afr[2];
#pragma unroll
    for (int ks2 = 0; ks2 < 2; ++ks2)
      afr[ks2] = __builtin_bit_cast(bf16x8_t,
          *reinterpret_cast<const s16x8_t*>(qrow + ks2 * 32 + lh * 8));
    s16x8_t qa = *reinterpret_cast<const s16x8_t*>(qrow + lh * 16);
    s16x8_t qb = *reinterpret_cast<const s16x8_t*>(qrow + lh * 16 + 8);
    float part = 0.f;
#pragma unroll
    for (int i = 0; i < 8; ++i) part += bf2f((unsigned short)qa[i]) * ksr[i];
#pragma unroll
    for (int i = 0; i < 8; ++i) part += bf2f((unsigned short)qb[i]) * ksr[8 + i];
    part += __shfl_xor(part, 16);
    part += __shfl_xor(part, 32);
#pragma unroll
    for (int j = 0; j < 4; ++j) {
      float dj = __shfl(part, lh * 4 + j);
      rden[m][j] = 1.0f / (dj + EPSV);
    }
#pragma unroll
    for (int ks2 = 0; ks2 < 2; ++ks2)
#pragma unroll
      for (int n = 0; n < 4; ++n)
        acc[m][n] = __builtin_amdgcn_mfma_f32_16x16x32_bf16(afr[ks2], bfrag[ks2][n], acc[m][n], 0, 0, 0);
  }

#pragma unroll
  for (int m = 0; m < 4; ++m)
#pragma unroll
    for (int n = 0; n < 4; ++n) {
      const int col = h * 64 + n * 16 + l15;
#pragma unroll
      for (int j = 0; j < 4; ++j) {
        const int row = rbase + m * 16 + lh * 4 + j;
        att[row * 1024 + col] = f2bf_bits(acc[m][n][j] * rden[m][j]);
      }
    }
}

// ---------------------------------------------------------------- launch
extern "C" void kernel_launch(void* const* d_in, const int* in_sizes, int n_in,
                              void* d_out, int out_size, void* d_ws, size_t ws_size,
                              hipStream_t stream) {
  const float* query = (const float*)d_in[0];
  const float* key   = (const float*)d_in[1];
  const float* value = (const float*)d_in[2];
  const float* Wq = (const float*)d_in[3];
  const float* bq = (const float*)d_in[4];
  const float* Wk = (const float*)d_in[5];
  const float* bk = (const float*)d_in[6];
  const float* Wv = (const float*)d_in[7];
  const float* bv = (const float*)d_in[8];
  const float* Wo = (const float*)d_in[9];
  const float* bo = (const float*)d_in[10];
  float* out = (float*)d_out;

  if (ws_size < 277889024ULL) return;
  char* ws = (char*)d_ws;
  unsigned short* Vbf = (unsigned short*)(ws + 0);          // value bf16; reused as att
  unsigned short* qf  = (unsigned short*)(ws + 67108864);
  unsigned short* kTf = (unsigned short*)(ws + 134217728);  // k transposed [b][h][d][t]
  unsigned short* vTf = (unsigned short*)(ws + 201326592);  // v transposed
  unsigned short* Wqb = (unsigned short*)(ws + 268435456);
  unsigned short* Wkb = Wqb + 1048576;
  unsigned short* Wvb = Wkb + 1048576;
  unsigned short* Wob = Wvb + 1048576;
  float* kvT  = (float*)(ws + 276824064);
  float* ksum = (float*)(ws + 277872640);

  unsigned short* Qbf = (unsigned short*)d_out;   // d_out doubles as bf16 scratch
  unsigned short* Kbf = Qbf + 33554432;

  hipMemsetAsync(kvT, 0, (size_t)(64 * 64 * 64 + 64 * 64) * sizeof(float), stream);

  convert3_f32_bf16<<<6144, 256, 0, stream>>>(query, key, value, Qbf, Kbf, Vbf);
  convertW_f32_bf16<<<2048, 256, 0, stream>>>(Wq, Wk, Wv, Wo, Wqb, Wkb, Wvb, Wob);

  gemm256<1, 0><<<512, 512, 0, stream>>>(Qbf, Wqb, bq, qf);   // q row-major
  gemm256<1, 2><<<512, 512, 0, stream>>>(Kbf, Wkb, bk, kTf);  // k transposed
  gemm256<0, 2><<<512, 512, 0, stream>>>(Vbf, Wvb, bv, vTf);  // v transposed

  kv_ksum_mfma<<<1024, 256, 0, stream>>>(kTf, vTf, kvT, ksum);

  attn_apply_kernel<<<2048, 256, 0, stream>>>(qf, kvT, ksum, Vbf);  // att -> Vbf

  gemm256<0, 1><<<512, 512, 0, stream>>>(Vbf, Wob, bo, out);  // final -> f32
}

// Round 12
// 595.262 us; speedup vs baseline: 1.0013x; 1.0013x over previous
//
#include <hip/hip_runtime.h>
#include <hip/hip_bf16.h>

typedef long long TLONG;
typedef float  f32x4_t  __attribute__((ext_vector_type(4)));
typedef short  s16x8_t  __attribute__((ext_vector_type(8)));
typedef short  s16x4_t  __attribute__((ext_vector_type(4)));
typedef __bf16 bf16x8_t __attribute__((ext_vector_type(8)));

#define MDIM 32768
#define NDIM 1024
#define KDIM 1024
#define EPSV 1e-6f

#define BARRIER() asm volatile("s_barrier" ::: "memory")
#define SBAR() __builtin_amdgcn_sched_barrier(0)

__device__ __forceinline__ unsigned short f2bf_bits(float f) {
  __hip_bfloat16 h = __float2bfloat16(f);
  return __builtin_bit_cast(unsigned short, h);
}
__device__ __forceinline__ float bf2f(unsigned short u) {
  unsigned int x = ((unsigned int)u) << 16;
  return __builtin_bit_cast(float, x);
}
// async global->LDS, 16B per lane. LDS dest must be wave-uniform base + lane*16.
__device__ __forceinline__ void load_lds16(const void* g, void* l) {
  __builtin_amdgcn_global_load_lds((const __attribute__((address_space(1))) void*)g,
                                   (__attribute__((address_space(3))) void*)l, 16, 0, 0);
}

// nt LOADS (f32 read exactly once -> keep out of L3); REGULAR stores (outputs
// are re-read by the GEMMs -> want L3 residency). [R8: nt stores cost +26MB refetch]
__device__ __forceinline__ void conv8(const float* __restrict__ in,
                                      unsigned short* __restrict__ out, TLONG i) {
  f32x4_t a = __builtin_nontemporal_load(reinterpret_cast<const f32x4_t*>(in + i));
  f32x4_t b = __builtin_nontemporal_load(reinterpret_cast<const f32x4_t*>(in + i + 4));
  s16x8_t o;
  o[0] = (short)f2bf_bits(a[0]); o[1] = (short)f2bf_bits(a[1]);
  o[2] = (short)f2bf_bits(a[2]); o[3] = (short)f2bf_bits(a[3]);
  o[4] = (short)f2bf_bits(b[0]); o[5] = (short)f2bf_bits(b[1]);
  o[6] = (short)f2bf_bits(b[2]); o[7] = (short)f2bf_bits(b[3]);
  *reinterpret_cast<s16x8_t*>(out + i) = o;
}

// ---------------------------------------------------------------- converts
__global__ __launch_bounds__(256) void convert3_f32_bf16(
    const float* __restrict__ a, const float* __restrict__ b, const float* __restrict__ c,
    unsigned short* __restrict__ oa, unsigned short* __restrict__ ob,
    unsigned short* __restrict__ oc) {
  int blk = blockIdx.x;
  const float* in; unsigned short* out;
  if (blk < 2048)      { in = a; out = oa; }
  else if (blk < 4096) { in = b; out = ob; blk -= 2048; }
  else                 { in = c; out = oc; blk -= 4096; }
  const TLONG n = 33554432LL;
  TLONG i = ((TLONG)blk * 256 + threadIdx.x) * 8;
  const TLONG stride = 2048LL * 256 * 8;
  for (; i < n; i += stride) conv8(in, out, i);
}
__global__ __launch_bounds__(256) void convertW_f32_bf16(
    const float* __restrict__ a, const float* __restrict__ b, const float* __restrict__ c,
    const float* __restrict__ d, unsigned short* __restrict__ oa,
    unsigned short* __restrict__ ob, unsigned short* __restrict__ oc,
    unsigned short* __restrict__ od) {
  int blk = blockIdx.x;
  const float* in; unsigned short* out;
  if (blk < 512)       { in = a; out = oa; }
  else if (blk < 1024) { in = b; out = ob; blk -= 512; }
  else if (blk < 1536) { in = c; out = oc; blk -= 1024; }
  else                 { in = d; out = od; blk -= 1536; }
  TLONG i = ((TLONG)blk * 256 + threadIdx.x) * 8;
  conv8(in, out, i);
}

// ---------------------------------------------------------------- GEMM 128x128, 2 blocks/CU
// C[m][n] = f(sum_k A[m][k]*W[n][k] + bias[n]); M=32768, N=K=1024.
// BM=BN=128, BK=64; 256 thr = 4 waves (2M x 2N); wave tile 64x64 = 4x4 frags.
// LDS 64 KiB = 2 buf x (A 16KB | B 16KB) -> 2 blocks/CU: independent blocks
// overlap each other's barrier/wait stalls (m114 mechanism).
// Counted-wait ladder per K-tile (R5-proven invariants):
//  P1: issue G1=[Af0-3 x2ks, Bf0-1 x2ks](12) + G2=[Bf2-3 x2ks](4) pinned;
//      stage B(kt+1)->buf q; bar; lgkm(4) [G1 done]; quad(A x B01); bar
//  P2: stage A(kt+2)->buf p [A-reads retired block-wide at P1's lgkm(4)+bar];
//      bar; lgkm(0) [G2 done]; quad(A x B23); vmcnt(4) [kt+1 fully landed,
//      A(kt+2) in flight - never 0 in-loop]; bar
template <int FMAP, int OUT>
__global__ __launch_bounds__(256, 2) void gemm128(
    const unsigned short* __restrict__ A, const unsigned short* __restrict__ W,
    const float* __restrict__ bias, void* __restrict__ Cout) {
  __shared__ short lds[32768];                    // [2 buf][A 8192 | B 8192] shorts
  const int bid = blockIdx.x;                     // 2048 blocks
  const int swz = (bid & 7) * 256 + (bid >> 3);   // XCD-chunked (2048%8==0)
  const int mt = swz >> 3;                        // 0..255
  const int nt = swz & 7;                         // 0..7

  const int tid = threadIdx.x;
  const int lane = tid & 63;
  const int w = tid >> 6;
  const int wr = w >> 1, wc = w & 1;
  const int l15 = lane & 15, lh = lane >> 4;

  const int arow0 = mt * 128, brow0 = nt * 128;

  // stage one full 128x64 tile (16KB = 1024 x 16B chunks, 4/thread), linear LDS
  // dest, inverse-swizzled source (slot ps holds col-group ps^(r&7)).
  auto stage_mat = [&](const unsigned short* __restrict__ src, int ldsOff,
                       int grow, int k0) {
#pragma unroll
    for (int i = 0; i < 4; ++i) {
      const int c = i * 256 + tid;                // 0..1023
      const int r = c >> 3, ps = c & 7;
      load_lds16(src + (grow + r) * KDIM + k0 + ((ps ^ (r & 7)) * 8),
                 &lds[ldsOff + c * 8]);
    }
  };

  f32x4_t acc[4][4];
#pragma unroll
  for (int m = 0; m < 4; ++m)
#pragma unroll
    for (int n = 0; n < 4; ++n) acc[m][n] = (f32x4_t)0.0f;

  s16x8_t Af[4][2], Bf[4][2];

  auto rdA = [&](int pb, int m, int ks) -> s16x8_t {
    const int row = wr * 64 + m * 16 + l15;
    return *reinterpret_cast<const s16x8_t*>(
        &lds[pb + row * 64 + (((ks * 4 + lh) ^ (row & 7)) * 8)]);
  };
  auto rdB = [&](int pb, int n, int ks) -> s16x8_t {
    const int row = wc * 64 + n * 16 + l15;
    return *reinterpret_cast<const s16x8_t*>(
        &lds[pb + 8192 + row * 64 + (((ks * 4 + lh) ^ (row & 7)) * 8)]);
  };
  auto quad = [&](int nl) {                       // A(all) x B[nl..nl+1]: 16 MFMA
    __builtin_amdgcn_s_setprio(1);
#pragma unroll
    for (int m = 0; m < 4; ++m)
#pragma unroll
      for (int n = 0; n < 2; ++n)
#pragma unroll
        for (int ks = 0; ks < 2; ++ks)
          acc[m][nl + n] = __builtin_amdgcn_mfma_f32_16x16x32_bf16(
              __builtin_bit_cast(bf16x8_t, Af[m][ks]),
              __builtin_bit_cast(bf16x8_t, Bf[nl + n][ks]),
              acc[m][nl + n], 0, 0, 0);
    __builtin_amdgcn_s_setprio(0);
  };

  // prologue: A(0),B(0) -> buf0; A(1) -> buf1 A (12 gloads/thread)
  stage_mat(A, 0,     arow0, 0);
  stage_mat(W, 8192,  brow0, 0);
  stage_mat(A, 16384, arow0, 64);
  asm volatile("s_waitcnt vmcnt(4)" ::: "memory");   // A0,B0 landed; A1 in flight
  SBAR();
  BARRIER();

  for (int kt = 0; kt < 16; ++kt) {
    const int p = kt & 1;
    const int pb = p * 16384, qb = 16384 - pb;
    const int k1 = ((kt + 1) & 15) * 64;
    const int k2 = ((kt + 2) & 15) * 64;   // wrapped tail: junk reload, never read
    // ---- P1: issue G1(12)+G2(4) pinned; stage B(kt+1)->buf q
#pragma unroll
    for (int m = 0; m < 4; ++m)
#pragma unroll
      for (int ks = 0; ks < 2; ++ks) Af[m][ks] = rdA(pb, m, ks);
#pragma unroll
    for (int n = 0; n < 2; ++n)
#pragma unroll
      for (int ks = 0; ks < 2; ++ks) Bf[n][ks] = rdB(pb, n, ks);
    SBAR();                                         // pin G1 (12 reads)
#pragma unroll
    for (int n = 2; n < 4; ++n)
#pragma unroll
      for (int ks = 0; ks < 2; ++ks) Bf[n][ks] = rdB(pb, n, ks);
    SBAR();                                         // pin G2 (4 reads)
    stage_mat(W, qb + 8192, brow0, k1);
    BARRIER();
    asm volatile("s_waitcnt lgkmcnt(4)" ::: "memory");   // G1 done (all A + B01)
    SBAR();
    quad(0);
    BARRIER();
    // ---- P2: stage A(kt+2)->buf p (A-readers retired block-wide at P1)
    stage_mat(A, pb, arow0, k2);
    BARRIER();
    asm volatile("s_waitcnt lgkmcnt(0)" ::: "memory");   // G2 done
    SBAR();
    quad(2);
    asm volatile("s_waitcnt vmcnt(4)" ::: "memory");     // kt+1 fully landed
    SBAR();
    BARRIER();
  }

  // epilogue: C/D layout col = lane&15, row = (lane>>4)*4 + j  [m89/m91]
#pragma unroll
  for (int n = 0; n < 4; ++n) {
    const int col = nt * 128 + wc * 64 + n * 16 + l15;
    const float bv = bias[col];
#pragma unroll
    for (int m = 0; m < 4; ++m) {
      const int row0 = mt * 128 + wr * 64 + m * 16 + lh * 4;
      if (OUT == 2) {
        const int b = row0 >> 13, tl = row0 & 8191;
        const int h = col >> 6, d = col & 63;
        s16x4_t o;
#pragma unroll
        for (int j = 0; j < 4; ++j) {
          float v = acc[m][n][j] + bv;
          if (FMAP) v = (v > 0.0f) ? (v + 1.0f) : __expf(v);
          o[j] = (short)f2bf_bits(v);
        }
        *reinterpret_cast<s16x4_t*>(
            reinterpret_cast<unsigned short*>(Cout) +
            (((b * 16 + h) * 64 + d) * 8192 + tl)) = o;
      } else {
#pragma unroll
        for (int j = 0; j < 4; ++j) {
          float v = acc[m][n][j] + bv;
          if (FMAP) v = (v > 0.0f) ? (v + 1.0f) : __expf(v);  // elu(x)+1
          if (OUT == 1)
            __builtin_nontemporal_store(v,                    // final f32: never re-read
                &reinterpret_cast<float*>(Cout)[(row0 + j) * NDIM + col]);
          else
            reinterpret_cast<unsigned short*>(Cout)[(row0 + j) * NDIM + col] = f2bf_bits(v);
        }
      }
    }
  }
}

// ---------------------------------------------------------------- kv + k_sum (MFMA, streaming)
// Inputs transposed: kT[bh][d][8192 t], vT[bh][e][8192 t] (bf16).
__global__ __launch_bounds__(256) void kv_ksum_mfma(
    const unsigned short* __restrict__ kT, const unsigned short* __restrict__ vT,
    float* __restrict__ kvT, float* __restrict__ ksum) {
  const int bid = blockIdx.x;
  const int bh = bid >> 4, ch = bid & 15;
  const int tid = threadIdx.x;
  const int lane = tid & 63, w = tid >> 6;
  const int l15 = lane & 15, lh = lane >> 4;
  const int dblk = (w >> 1) * 32, eblk = (w & 1) * 32;

  f32x4_t acc[2][2];
#pragma unroll
  for (int m = 0; m < 2; ++m)
#pragma unroll
    for (int n = 0; n < 2; ++n) acc[m][n] = (f32x4_t)0.0f;
  float ks0 = 0.f, ks1 = 0.f;

  const int tbase = ch * 512 + lh * 8;
  const unsigned short* ka = kT + (bh * 64 + dblk + l15) * 8192 + tbase;
  const unsigned short* va = vT + (bh * 64 + eblk + l15) * 8192 + tbase;

  for (int t0 = 0; t0 < 512; t0 += 32) {
    s16x8_t ar[2], br[2];
#pragma unroll
    for (int m = 0; m < 2; ++m)
      ar[m] = *reinterpret_cast<const s16x8_t*>(ka + m * 16 * 8192 + t0);
#pragma unroll
    for (int n = 0; n < 2; ++n)
      br[n] = *reinterpret_cast<const s16x8_t*>(va + n * 16 * 8192 + t0);
#pragma unroll
    for (int m = 0; m < 2; ++m)
#pragma unroll
      for (int n = 0; n < 2; ++n)
        acc[m][n] = __builtin_amdgcn_mfma_f32_16x16x32_bf16(
            __builtin_bit_cast(bf16x8_t, ar[m]),
            __builtin_bit_cast(bf16x8_t, br[n]), acc[m][n], 0, 0, 0);
    if (eblk == 0) {
#pragma unroll
      for (int i = 0; i < 8; ++i) ks0 += bf2f((unsigned short)ar[0][i]);
#pragma unroll
      for (int i = 0; i < 8; ++i) ks1 += bf2f((unsigned short)ar[1][i]);
    }
  }

  if (eblk == 0) {
    ks0 += __shfl_xor(ks0, 16); ks0 += __shfl_xor(ks0, 32);
    ks1 += __shfl_xor(ks1, 16); ks1 += __shfl_xor(ks1, 32);
    if (lh == 0) {
      atomicAdd(&ksum[bh * 64 + dblk + l15], ks0);
      atomicAdd(&ksum[bh * 64 + dblk + 16 + l15], ks1);
    }
  }
#pragma unroll
  for (int n = 0; n < 2; ++n) {
    const int e = eblk + n * 16 + l15;
#pragma unroll
    for (int m = 0; m < 2; ++m) {
      const int d0 = dblk + m * 16 + lh * 4;
#pragma unroll
      for (int j = 0; j < 4; ++j)
        atomicAdd(&kvT[(bh * 64 + e) * 64 + d0 + j], acc[m][n][j]);
    }
  }
}

// ---------------------------------------------------------------- out = q@kv / (q.ksum+eps)
__global__ __launch_bounds__(256) void attn_apply_kernel(
    const unsigned short* __restrict__ qf, const float* __restrict__ kvT,
    const float* __restrict__ ksum, unsigned short* __restrict__ att) {
  const int bid = blockIdx.x;                     // 2048
  const int swz = (bid & 7) * 256 + (bid >> 3);
  const int bh = swz >> 5;
  const int tile = swz & 31;
  const int b = bh >> 4, h = bh & 15;
  const int tid = threadIdx.x;
  const int lane = tid & 63, w = tid >> 6;
  const int l15 = lane & 15, lh = lane >> 4;

  float ksr[16];
#pragma unroll
  for (int i = 0; i < 16; ++i) ksr[i] = ksum[bh * 64 + lh * 16 + i];

  bf16x8_t bfrag[2][4];
#pragma unroll
  for (int ks2 = 0; ks2 < 2; ++ks2)
#pragma unroll
    for (int n = 0; n < 4; ++n) {
      const float* p = kvT + (bh * 64 + n * 16 + l15) * 64 + ks2 * 32 + lh * 8;
      f32x4_t p0 = *reinterpret_cast<const f32x4_t*>(p);
      f32x4_t p1 = *reinterpret_cast<const f32x4_t*>(p + 4);
      s16x8_t t;
      t[0] = (short)f2bf_bits(p0[0]); t[1] = (short)f2bf_bits(p0[1]);
      t[2] = (short)f2bf_bits(p0[2]); t[3] = (short)f2bf_bits(p0[3]);
      t[4] = (short)f2bf_bits(p1[0]); t[5] = (short)f2bf_bits(p1[1]);
      t[6] = (short)f2bf_bits(p1[2]); t[7] = (short)f2bf_bits(p1[3]);
      bfrag[ks2][n] = __builtin_bit_cast(bf16x8_t, t);
    }

  const int rbase = b * 8192 + tile * 256 + w * 64;
  f32x4_t acc[4][4];
#pragma unroll
  for (int m = 0; m < 4; ++m)
#pragma unroll
    for (int n = 0; n < 4; ++n) acc[m][n] = (f32x4_t)0.0f;
  float rden[4][4];

#pragma unroll
  for (int m = 0; m < 4; ++m) {
    const int row = rbase + m * 16 + l15;
    const unsigned short* qrow = qf + row * 1024 + h * 64;
    bf16x8_t afr[2];
#pragma unroll
    for (int ks2 = 0; ks2 < 2; ++ks2)
      afr[ks2] = __builtin_bit_cast(bf16x8_t,
          *reinterpret_cast<const s16x8_t*>(qrow + ks2 * 32 + lh * 8));
    s16x8_t qa = *reinterpret_cast<const s16x8_t*>(qrow + lh * 16);
    s16x8_t qb = *reinterpret_cast<const s16x8_t*>(qrow + lh * 16 + 8);
    float part = 0.f;
#pragma unroll
    for (int i = 0; i < 8; ++i) part += bf2f((unsigned short)qa[i]) * ksr[i];
#pragma unroll
    for (int i = 0; i < 8; ++i) part += bf2f((unsigned short)qb[i]) * ksr[8 + i];
    part += __shfl_xor(part, 16);
    part += __shfl_xor(part, 32);
#pragma unroll
    for (int j = 0; j < 4; ++j) {
      float dj = __shfl(part, lh * 4 + j);
      rden[m][j] = 1.0f / (dj + EPSV);
    }
#pragma unroll
    for (int ks2 = 0; ks2 < 2; ++ks2)
#pragma unroll
      for (int n = 0; n < 4; ++n)
        acc[m][n] = __builtin_amdgcn_mfma_f32_16x16x32_bf16(afr[ks2], bfrag[ks2][n], acc[m][n], 0, 0, 0);
  }

#pragma unroll
  for (int m = 0; m < 4; ++m)
#pragma unroll
    for (int n = 0; n < 4; ++n) {
      const int col = h * 64 + n * 16 + l15;
#pragma unroll
      for (int j = 0; j < 4; ++j) {
        const int row = rbase + m * 16 + lh * 4 + j;
        att[row * 1024 + col] = f2bf_bits(acc[m][n][j] * rden[m][j]);
      }
    }
}

// ---------------------------------------------------------------- launch
extern "C" void kernel_launch(void* const* d_in, const int* in_sizes, int n_in,
                              void* d_out, int out_size, void* d_ws, size_t ws_size,
                              hipStream_t stream) {
  const float* query = (const float*)d_in[0];
  const float* key   = (const float*)d_in[1];
  const float* value = (const float*)d_in[2];
  const float* Wq = (const float*)d_in[3];
  const float* bq = (const float*)d_in[4];
  const float* Wk = (const float*)d_in[5];
  const float* bk = (const float*)d_in[6];
  const float* Wv = (const float*)d_in[7];
  const float* bv = (const float*)d_in[8];
  const float* Wo = (const float*)d_in[9];
  const float* bo = (const float*)d_in[10];
  float* out = (float*)d_out;

  if (ws_size < 277889024ULL) return;
  char* ws = (char*)d_ws;
  unsigned short* Vbf = (unsigned short*)(ws + 0);          // value bf16; reused as att
  unsigned short* qf  = (unsigned short*)(ws + 67108864);
  unsigned short* kTf = (unsigned short*)(ws + 134217728);  // k transposed [b][h][d][t]
  unsigned short* vTf = (unsigned short*)(ws + 201326592);  // v transposed
  unsigned short* Wqb = (unsigned short*)(ws + 268435456);
  unsigned short* Wkb = Wqb + 1048576;
  unsigned short* Wvb = Wkb + 1048576;
  unsigned short* Wob = Wvb + 1048576;
  float* kvT  = (float*)(ws + 276824064);
  float* ksum = (float*)(ws + 277872640);

  unsigned short* Qbf = (unsigned short*)d_out;   // d_out doubles as bf16 scratch
  unsigned short* Kbf = Qbf + 33554432;

  hipMemsetAsync(kvT, 0, (size_t)(64 * 64 * 64 + 64 * 64) * sizeof(float), stream);

  convert3_f32_bf16<<<6144, 256, 0, stream>>>(query, key, value, Qbf, Kbf, Vbf);
  convertW_f32_bf16<<<2048, 256, 0, stream>>>(Wq, Wk, Wv, Wo, Wqb, Wkb, Wvb, Wob);

  gemm128<1, 0><<<2048, 256, 0, stream>>>(Qbf, Wqb, bq, qf);   // q row-major
  gemm128<1, 2><<<2048, 256, 0, stream>>>(Kbf, Wkb, bk, kTf);  // k transposed
  gemm128<0, 2><<<2048, 256, 0, stream>>>(Vbf, Wvb, bv, vTf);  // v transposed

  kv_ksum_mfma<<<1024, 256, 0, stream>>>(kTf, vTf, kvT, ksum);

  attn_apply_kernel<<<2048, 256, 0, stream>>>(qf, kvT, ksum, Vbf);  // att -> Vbf

  gemm128<0, 1><<<2048, 256, 0, stream>>>(Vbf, Wob, bo, out);  // final -> f32
}